// Round 4
// baseline (137.567 us; speedup 1.0000x reference)
//
#include <hip/hip_runtime.h>
#include <hip/hip_bf16.h>

// Problem: B=8, A=512, IN=OUT=1024, N_OPT=16, fp32 in/out.
// out[b,a,i] = sum_j (sum_n sp[b,n] W[n,i,j]) x[b,a,j] + sum_n sp[b,n] bias[n,i]
//
// R3->R4: flatmm rewrite. Prep now emits k-octet-major transposed bf16 layouts
//   xt[b][c][r][8k], wt[b][c][i][8k]  (c = k/8, 16B chunks)
// so a 32x32x16 MFMA fragment is ONE fully-coalesced global_load_dwordx4
// (2 x 512B segments/wave). GEMM has NO LDS and NO barriers: per K=16 step,
// 3 direct loads + 2 MFMA, pipelined by the compiler via vmcnt. XCD swizzle
// (b = bid&7) keeps each batch's 3MB working set in one XCD's L2.

#define B_SZ 8
#define A_SZ 512
#define IN_F 1024
#define OUT_F 1024
#define N_OPT 16

typedef short short8 __attribute__((ext_vector_type(8)));
typedef float floatx16 __attribute__((ext_vector_type(16)));

__device__ __forceinline__ unsigned short f2bf(float f) {
    unsigned int u = __builtin_bit_cast(unsigned int, f);
    u += 0x7fffu + ((u >> 16) & 1u);   // RNE; inputs finite
    return (unsigned short)(u >> 16);
}

// ---------------------------------------------------------------------------
// Kernel 1: prep.
//   blocks [0,1024):     weight mix + transpose -> wt[b][c][i][8] bf16
//   blocks [1024,3072):  x convert + transpose  -> xt[b][c][r][8] bf16
//   blocks [3072,3080):  bias mixing -> fp32 bmixed[b][i]
// ---------------------------------------------------------------------------
__global__ __launch_bounds__(256) void selin_prep(
    const float* __restrict__ x, const float* __restrict__ sp,
    const float* __restrict__ weight, const float* __restrict__ bias,
    unsigned short* __restrict__ wt, unsigned short* __restrict__ xt,
    float* __restrict__ bmixed)
{
    const int bid = blockIdx.x;
    const int tid = threadIdx.x;

    if (bid < 1024) {
        // --- weight mix + transpose ---
        // Block covers 8 rows (i) x 128 k (32 quads). 128 ib x 8 kb blocks.
        __shared__ float sps[B_SZ * N_OPT];
        if (tid < B_SZ * N_OPT) sps[tid] = sp[tid];
        __syncthreads();
        const int ib = bid & 127, kb = bid >> 7;
        const int i0 = ib * 8, q0 = kb * 32;
        const int i_loc = tid & 7;            // row within block
        const int q_loc = tid >> 3;           // k-quad within block (0..31)
        const float4* w4 = (const float4*)weight;
        // reads: per n, 8 segments of 128B (8 consecutive quads per row)
        float4 w[N_OPT];
#pragma unroll
        for (int n = 0; n < N_OPT; n++)
            w[n] = w4[(size_t)n * (IN_F * OUT_F / 4) + (i0 + i_loc) * (IN_F / 4) + q0 + q_loc];
        // write target: wt chunk (c = k/8, i), 8B half-chunks.
        // lanes grouped by c -> 128B contiguous segments.
        const int c_glob = kb * 16 + (q_loc >> 1);
        ushort4* wt4 = (ushort4*)wt;
        const size_t widx = ((size_t)c_glob * OUT_F + i0 + i_loc) * 2 + (q_loc & 1);
#pragma unroll
        for (int b = 0; b < B_SZ; b++) {
            float ax = 0.f, ay = 0.f, az = 0.f, aw = 0.f;
#pragma unroll
            for (int n = 0; n < N_OPT; n++) {
                float s = sps[b * N_OPT + n];
                ax += s * w[n].x; ay += s * w[n].y;
                az += s * w[n].z; aw += s * w[n].w;
            }
            wt4[(size_t)b * (OUT_F * IN_F / 4) + widx] =
                make_ushort4(f2bf(ax), f2bf(ay), f2bf(az), f2bf(aw));
        }
    } else if (bid < 3072) {
        // --- x convert + transpose ---
        // Block covers 16 r x 16 c (one octet per thread).
        // grid: 8 b * 32 rb * 8 cb = 2048 blocks.
        const int t2 = bid - 1024;
        const int b  = t2 >> 8;
        const int rem = t2 & 255;
        const int r0 = (rem & 31) * 16;
        const int c0 = (rem >> 5) * 16;
        const int w  = tid >> 6, l = tid & 63;
        const int r  = r0 + w * 4 + (l >> 4);
        const int c  = c0 + (l & 15);
        // read 32B/lane; lanes 0-15 share r, consecutive c -> 512B segments
        const float4* x4 = (const float4*)x;
        const size_t rbase = ((size_t)b * A_SZ + r) * (IN_F / 4) + c * 2;
        float4 v0 = x4[rbase], v1 = x4[rbase + 1];
        short8 o;
        o[0] = (short)f2bf(v0.x); o[1] = (short)f2bf(v0.y);
        o[2] = (short)f2bf(v0.z); o[3] = (short)f2bf(v0.w);
        o[4] = (short)f2bf(v1.x); o[5] = (short)f2bf(v1.y);
        o[6] = (short)f2bf(v1.z); o[7] = (short)f2bf(v1.w);
        // write 16B chunk (c, r); lanes grouped by c -> 16 segments of 64B
        *(short8*)(xt + ((size_t)b * 65536 + (size_t)c * A_SZ + r) * 8) = o;
    } else {
        // --- bias mixing ---
        __shared__ float sps[B_SZ * N_OPT];
        if (tid < B_SZ * N_OPT) sps[tid] = sp[tid];
        __syncthreads();
        const int idx = (bid - 3072) * 256 + tid;    // float4 over 8x1024
        const int b = idx >> 8, i4 = idx & 255;
        const float4* bias4 = (const float4*)bias;
        float ax = 0.f, ay = 0.f, az = 0.f, aw = 0.f;
#pragma unroll
        for (int n = 0; n < N_OPT; n++) {
            float s = sps[b * N_OPT + n];
            float4 v = bias4[n * 256 + i4];
            ax += s * v.x; ay += s * v.y; az += s * v.z; aw += s * v.w;
        }
        ((float4*)bmixed)[idx] = make_float4(ax, ay, az, aw);
    }
}

// ---------------------------------------------------------------------------
// Kernel 2: LDS-free batched GEMM. C[b] = X[b] * Wm[b]^T + bias.
// Wave tile 32(m) x 64(n): per K=16 step, 1 A-frag load + 2 B-frag loads
// (each one coalesced dwordx4) + 2 v_mfma_f32_32x32x16_bf16. No LDS/barriers.
// Block = 4 waves = 32m x 256n. Grid: 8 b * 16 ms * 4 ns = 512 blocks,
// b = bid&7 for XCD-L2 locality.
// ---------------------------------------------------------------------------
__global__ __launch_bounds__(256) void selin_gemm(
    const unsigned short* __restrict__ xt, const unsigned short* __restrict__ wt,
    const float* __restrict__ bmixed, float* __restrict__ out)
{
    const int tid  = threadIdx.x;
    const int bid  = blockIdx.x;
    const int b    = bid & 7;
    const int t    = bid >> 3;        // 0..63
    const int ms   = t & 15;          // m-strip (32 rows)
    const int ns   = t >> 4;          // n-super (256 cols)
    const int wv   = tid >> 6;
    const int lane = tid & 63;
    const int lm   = lane & 31;       // row/col within frag
    const int kq   = lane >> 5;       // k-octet half

    const int r0 = ms * 32;
    const int n0 = ns * 256 + wv * 64;

    const unsigned short* xtb = xt + (size_t)b * 524288;   // 128c*512r*8
    const unsigned short* wtb = wt + (size_t)b * 1048576;  // 128c*1024i*8

    // fragment byte-positions (ushort units), advance by s (K=16 steps)
    const unsigned short* ap = xtb + (size_t)kq * 4096 + (size_t)(r0 + lm) * 8;
    const unsigned short* bp = wtb + (size_t)kq * 8192 + (size_t)(n0 + lm) * 8;

    floatx16 acc0 = {0.f}, acc1 = {0.f};
#pragma unroll
    for (int i = 0; i < 16; i++) { acc0[i] = 0.f; acc1[i] = 0.f; }

#pragma unroll 4
    for (int s = 0; s < 64; s++) {
        short8 a  = *(const short8*)(ap + (size_t)s * 8192);
        short8 b0 = *(const short8*)(bp + (size_t)s * 16384);
        short8 b1 = *(const short8*)(bp + (size_t)s * 16384 + 256);  // +32 cols
        acc0 = __builtin_amdgcn_mfma_f32_32x32x16_bf16(a, b0, acc0, 0, 0, 0);
        acc1 = __builtin_amdgcn_mfma_f32_32x32x16_bf16(a, b1, acc1, 0, 0, 0);
    }

    // epilogue: 32x32 C/D layout col=lane&31, row=(reg&3)+8*(reg>>2)+4*(lane>>5)
    const int gcol0 = n0 + lm;
    const float bv0 = bmixed[b * OUT_F + gcol0];
    const float bv1 = bmixed[b * OUT_F + gcol0 + 32];
#pragma unroll
    for (int reg = 0; reg < 16; reg++) {
        const int grow = r0 + (reg & 3) + 8 * (reg >> 2) + 4 * kq;
        float* op = out + ((size_t)b * A_SZ + grow) * OUT_F + gcol0;
        op[0]  = acc0[reg] + bv0;
        op[32] = acc1[reg] + bv1;
    }
}

extern "C" void kernel_launch(void* const* d_in, const int* in_sizes, int n_in,
                              void* d_out, int out_size, void* d_ws, size_t ws_size,
                              hipStream_t stream) {
    const float* x      = (const float*)d_in[0];  // [8,512,1024]
    const float* sp     = (const float*)d_in[1];  // [8,16]
    const float* weight = (const float*)d_in[2];  // [16,1024,1024]
    const float* bias   = (const float*)d_in[3];  // [16,1024]
    float* out = (float*)d_out;                   // [8,512,1024]

    // workspace: wt bf16 16MB | xt bf16 8MB | bmixed fp32 32KB
    unsigned short* wt  = (unsigned short*)d_ws;
    unsigned short* xt  = wt + (size_t)B_SZ * OUT_F * IN_F;
    float* bmixed       = (float*)(xt + (size_t)B_SZ * A_SZ * IN_F);

    selin_prep<<<3080, 256, 0, stream>>>(x, sp, weight, bias, wt, xt, bmixed);
    selin_gemm<<<512, 256, 0, stream>>>(xt, wt, bmixed, out);
}

// Round 5
// 129.959 us; speedup vs baseline: 1.0585x; 1.0585x over previous
//
#include <hip/hip_runtime.h>
#include <hip/hip_bf16.h>

// Problem: B=8, A=512, IN=OUT=1024, N_OPT=16, fp32 in/out.
// out[b,a,i] = sum_j (sum_n sp[b,n] W[n,i,j]) x[b,a,j] + sum_n sp[b,n] bias[n,i]
//
// Strategy: mix weights once (reads W 64MB exactly once), cast to bf16,
// then 8 batched MFMA GEMMs (C = X * Wm^T), bias folded into epilogue.
//
// R4->R5: revert flatmm (scattered prep writes + 384MB L2 gemm traffic lost
// to R3's LDS path). Back to R3 structure with: (a) gemm BK=64 as two 32-k
// sub-panels (same m97 bank-safe layout, half the barriers), (b) prep
// consolidated to 1032 blocks (x-convert folded into weight-mix blocks).

#define B_SZ 8
#define A_SZ 512
#define IN_F 1024
#define OUT_F 1024
#define N_OPT 16

typedef short short8 __attribute__((ext_vector_type(8)));
typedef float floatx4 __attribute__((ext_vector_type(4)));

__device__ __forceinline__ unsigned short f2bf(float f) {
    unsigned int u = __builtin_bit_cast(unsigned int, f);
    u += 0x7fffu + ((u >> 16) & 1u);   // RNE; inputs finite
    return (unsigned short)(u >> 16);
}

#define GLOBAL_LOAD_LDS16(g, l)                                                    \
    __builtin_amdgcn_global_load_lds(                                              \
        (const __attribute__((address_space(1))) void*)(g),                        \
        (__attribute__((address_space(3))) void*)(l), 16, 0, 0)

// ---------------------------------------------------------------------------
// Kernel 1: prep (1032 blocks).
//   blocks [0,1024):   weight mixing -> bf16 wm [8][1024][1024]  (coalesced)
//                      + x fp32->bf16 slice (4 float4/thread)
//   blocks [1024,1032): bias mixing -> fp32 bmixed [8][1024]
// ---------------------------------------------------------------------------
__global__ __launch_bounds__(256) void selin_prep(
    const float* __restrict__ x, const float* __restrict__ sp,
    const float* __restrict__ weight, const float* __restrict__ bias,
    unsigned short* __restrict__ wm, unsigned short* __restrict__ xbf,
    float* __restrict__ bmixed)
{
    const int bid = blockIdx.x;
    const int tid = threadIdx.x;

    if (bid < 1024) {
        __shared__ float sps[B_SZ * N_OPT];
        if (tid < B_SZ * N_OPT) sps[tid] = sp[tid];
        __syncthreads();
        // --- weight mixing: fully coalesced read/write streams ---
        const int e4 = bid * 256 + tid;              // float4 index into 1024x1024
        const float4* w4 = (const float4*)weight;
        float4 w[N_OPT];
#pragma unroll
        for (int n = 0; n < N_OPT; n++)
            w[n] = w4[(size_t)n * (IN_F * OUT_F / 4) + e4];
#pragma unroll
        for (int b = 0; b < B_SZ; b++) {
            float ax = 0.f, ay = 0.f, az = 0.f, aw = 0.f;
#pragma unroll
            for (int n = 0; n < N_OPT; n++) {
                float s = sps[b * N_OPT + n];
                ax += s * w[n].x; ay += s * w[n].y;
                az += s * w[n].z; aw += s * w[n].w;
            }
            ushort4 o = make_ushort4(f2bf(ax), f2bf(ay), f2bf(az), f2bf(aw));
            ((ushort4*)wm)[(size_t)b * (IN_F * OUT_F / 4) + e4] = o;
        }
        // --- x conversion slice: 1,048,576 float4 over 1024 blocks ---
#pragma unroll
        for (int j = 0; j < 4; j++) {
            const int idx = bid * 1024 + j * 256 + tid;
            float4 v = ((const float4*)x)[idx];
            ((ushort4*)xbf)[idx] =
                make_ushort4(f2bf(v.x), f2bf(v.y), f2bf(v.z), f2bf(v.w));
        }
    } else {
        __shared__ float sps[B_SZ * N_OPT];
        if (tid < B_SZ * N_OPT) sps[tid] = sp[tid];
        __syncthreads();
        const int idx = (bid - 1024) * 256 + tid;    // float4 over 8x1024
        const int b = idx >> 8, i4 = idx & 255;
        const float4* bias4 = (const float4*)bias;
        float ax = 0.f, ay = 0.f, az = 0.f, aw = 0.f;
#pragma unroll
        for (int n = 0; n < N_OPT; n++) {
            float s = sps[b * N_OPT + n];
            float4 v = bias4[n * 256 + i4];
            ax += s * v.x; ay += s * v.y; az += s * v.z; aw += s * v.w;
        }
        ((float4*)bmixed)[idx] = make_float4(ax, ay, az, aw);
    }
}

// ---------------------------------------------------------------------------
// Kernel 2: batched GEMM, C[b] = X[b] (512x1024) * Wm[b]^T (1024x1024) + bias.
// Tile 64x64, BK=64 staged as two 32-k sub-panels (m97 bank-safe 64B row
// stride). 4 waves in 2x2; each wave 32x32 = 2x2 frags of 16x16x32 MFMA,
// 2 k-halves per barrier pair -> 16 barrier pairs (vs 32 at BK=32).
// Grid: 1024 blocks (4/CU, 16KB LDS); b = bid&7 XCD-L2 swizzle.
// ---------------------------------------------------------------------------
__global__ __launch_bounds__(256) void selin_gemm(
    const unsigned short* __restrict__ xbf, const unsigned short* __restrict__ wm,
    const float* __restrict__ bmixed, float* __restrict__ out)
{
    __shared__ __align__(16) unsigned short As[2][64 * 32];   // 2 x 4 KB
    __shared__ __align__(16) unsigned short Bs[2][64 * 32];   // 2 x 4 KB

    const int tid = threadIdx.x;
    const int bid = blockIdx.x;
    const int b   = bid & 7;          // XCD swizzle: same b -> same XCD
    const int t   = bid >> 3;         // 0..127
    const int mb  = t & 7;            // 8 m-blocks of 64 rows
    const int nb  = t >> 3;           // 16 n-blocks of 64 cols
    const int m0  = mb * 64, n0 = nb * 64;

    const unsigned short* Ag = xbf + ((size_t)b * A_SZ  + m0) * IN_F;
    const unsigned short* Bg = wm  + ((size_t)b * OUT_F + n0) * IN_F;

    // 64x32 sub-panel = 4KB = 256 16B-chunks; one chunk per thread per panel.
    const int ga = (tid >> 2) * IN_F + (tid & 3) * 8;   // + k at use

    const int lane = tid & 63;
    const int wv   = tid >> 6;
    const int wmi  = wv >> 1, wni = wv & 1;   // 2x2 wave grid: 32 rows x 32 cols
    const int lm   = lane & 15, kq = lane >> 4;

    floatx4 acc[2][2];
#pragma unroll
    for (int i = 0; i < 2; i++)
#pragma unroll
        for (int j = 0; j < 2; j++)
            acc[i][j] = (floatx4){0.f, 0.f, 0.f, 0.f};

    for (int k0 = 0; k0 < IN_F; k0 += 64) {
        GLOBAL_LOAD_LDS16(Ag + ga + k0,      &As[0][tid * 8]);
        GLOBAL_LOAD_LDS16(Ag + ga + k0 + 32, &As[1][tid * 8]);
        GLOBAL_LOAD_LDS16(Bg + ga + k0,      &Bs[0][tid * 8]);
        GLOBAL_LOAD_LDS16(Bg + ga + k0 + 32, &Bs[1][tid * 8]);
        __syncthreads();   // staging complete (barrier drains vmcnt)

#pragma unroll
        for (int kh = 0; kh < 2; kh++) {
            short8 a[2], bb[2];
#pragma unroll
            for (int mi = 0; mi < 2; mi++)
                a[mi] = *(const short8*)&As[kh][(wmi * 32 + mi * 16 + lm) * 32 + kq * 8];
#pragma unroll
            for (int ni = 0; ni < 2; ni++)
                bb[ni] = *(const short8*)&Bs[kh][(wni * 32 + ni * 16 + lm) * 32 + kq * 8];

#pragma unroll
            for (int mi = 0; mi < 2; mi++)
#pragma unroll
                for (int ni = 0; ni < 2; ni++)
                    acc[mi][ni] = __builtin_amdgcn_mfma_f32_16x16x32_bf16(
                        a[mi], bb[ni], acc[mi][ni], 0, 0, 0);
        }
        __syncthreads();   // reads done before next staging overwrites LDS
    }

    // epilogue: C/D layout col=lane&15, row=(lane>>4)*4+reg
#pragma unroll
    for (int ni = 0; ni < 2; ni++) {
        const int gcol = n0 + wni * 32 + ni * 16 + lm;
        const float bv = bmixed[b * OUT_F + gcol];
#pragma unroll
        for (int mi = 0; mi < 2; mi++) {
            const int grow = m0 + wmi * 32 + mi * 16 + kq * 4;
            float* op = out + ((size_t)b * A_SZ + grow) * OUT_F + gcol;
#pragma unroll
            for (int r = 0; r < 4; r++)
                op[(size_t)r * OUT_F] = acc[mi][ni][r] + bv;
        }
    }
}

extern "C" void kernel_launch(void* const* d_in, const int* in_sizes, int n_in,
                              void* d_out, int out_size, void* d_ws, size_t ws_size,
                              hipStream_t stream) {
    const float* x      = (const float*)d_in[0];  // [8,512,1024]
    const float* sp     = (const float*)d_in[1];  // [8,16]
    const float* weight = (const float*)d_in[2];  // [16,1024,1024]
    const float* bias   = (const float*)d_in[3];  // [16,1024]
    float* out = (float*)d_out;                   // [8,512,1024]

    // workspace layout: wm bf16 16MB | xbf bf16 8MB | bmixed fp32 32KB
    unsigned short* wm  = (unsigned short*)d_ws;
    unsigned short* xbf = wm + (size_t)B_SZ * OUT_F * IN_F;
    float* bmixed       = (float*)(xbf + (size_t)B_SZ * A_SZ * IN_F);

    selin_prep<<<1032, 256, 0, stream>>>(x, sp, weight, bias, wm, xbf, bmixed);
    selin_gemm<<<1024, 256, 0, stream>>>(xbf, wm, bmixed, out);
}